// Round 1
// baseline (246.485 us; speedup 1.0000x reference)
//
#include <hip/hip_runtime.h>
#include <stdint.h>

#define T_TOK 4096
#define E_DIM 1024
#define H_N   16
#define D_HD  64
#define NSEG  8

typedef unsigned short u16;
typedef __bf16          bf16x8 __attribute__((ext_vector_type(8)));
typedef float           f32x4  __attribute__((ext_vector_type(4)));
typedef unsigned short  us8    __attribute__((ext_vector_type(8)));
typedef unsigned short  us4    __attribute__((ext_vector_type(4)));

__device__ __forceinline__ u16 f2bf(float f) {
  uint32_t u = __builtin_bit_cast(uint32_t, f);
  u += 0x7FFFu + ((u >> 16) & 1u);
  return (u16)(u >> 16);
}

__device__ __forceinline__ f32x4 mfma16(us8 a, us8 b, f32x4 c) {
  return __builtin_amdgcn_mfma_f32_16x16x32_bf16(
      __builtin_bit_cast(bf16x8, a), __builtin_bit_cast(bf16x8, b), c, 0, 0, 0);
}

__device__ __forceinline__ void async_load16(const void* g, void* l) {
  __builtin_amdgcn_global_load_lds(
      (const __attribute__((address_space(1))) void*)g,
      (__attribute__((address_space(3))) void*)l, 16, 0, 0);
}

// ---------------- fp32 -> bf16 conversion (hidden, Wqkv fused, Wo) ----------
__global__ __launch_bounds__(256) void cvt_all(
    const float* __restrict__ hs, const float* __restrict__ wq,
    const float* __restrict__ wk, const float* __restrict__ wv,
    const float* __restrict__ wo,
    u16* __restrict__ xb, u16* __restrict__ wqkv, u16* __restrict__ wob) {
  const int NH = T_TOK * E_DIM / 4;   // 1048576 float4s
  const int NW = E_DIM * E_DIM / 4;   // 262144 float4s
  int i = blockIdx.x * 256 + threadIdx.x;
  const float4* src; u16* dst; size_t off;
  if (i < NH)            { src = (const float4*)hs; dst = xb;   off = i; }
  else if (i < NH+NW)    { src = (const float4*)wq; dst = wqkv; off = i - NH;          src += off; off += 0;      goto L; }
  else if (i < NH+2*NW)  { src = (const float4*)wk; dst = wqkv; off = i - NH - NW;     src += off; off += NW;     goto L; }
  else if (i < NH+3*NW)  { src = (const float4*)wv; dst = wqkv; off = i - NH - 2*NW;   src += off; off += 2*NW;   goto L; }
  else                   { src = (const float4*)wo; dst = wob;  off = i - NH - 3*NW;   src += off;                goto L; }
  src += off;
L:
  float4 v = *src;
  us4 o;
  o[0] = f2bf(v.x); o[1] = f2bf(v.y); o[2] = f2bf(v.z); o[3] = f2bf(v.w);
  *(us4*)(dst + off * 4) = o;
}

// ---------------- bf16 GEMM: C[M,N] = A[M,K] * B[N,K]^T + bias --------------
// MODE 0: N=3072, split into Q/K/V bf16 with bq/bk/bv biases
// MODE 1: fp32 out + bias0
template <int MODE>
__global__ __launch_bounds__(256, 2) void gemm_bt(
    const u16* __restrict__ A, const u16* __restrict__ B,
    int M, int N, int K,
    const float* __restrict__ bias0, const float* __restrict__ bias1,
    const float* __restrict__ bias2,
    u16* __restrict__ out_q, u16* __restrict__ out_k, u16* __restrict__ out_v,
    float* __restrict__ out_f) {
  __shared__ u16 As[2][128 * 32];
  __shared__ u16 Bs[2][128 * 32];

  const int nbn = N / 128;
  int bm = blockIdx.x / nbn, bn = blockIdx.x % nbn;
  int m0 = bm * 128, n0 = bn * 128;
  int tid = threadIdx.x, lane = tid & 63, wave = tid >> 6;
  int wr = wave >> 1, wc = wave & 1;

  f32x4 acc[4][4] = {};

  auto stage = [&](int bufi, int k0) {
#pragma unroll
    for (int r = 0; r < 2; ++r) {
      int chunk = r * 4 + wave;                 // 1KB chunk, wave-uniform
      int elem = chunk * 512 + lane * 8;        // elems into 128x32 tile
      int row = elem >> 5, kc = elem & 31;
      async_load16(A + (size_t)(m0 + row) * K + k0 + kc, (char*)As[bufi] + chunk * 1024);
      async_load16(B + (size_t)(n0 + row) * K + k0 + kc, (char*)Bs[bufi] + chunk * 1024);
    }
  };

  stage(0, 0);
  __syncthreads();
  int NT = K / 32;
  int lrow = lane & 15, lk = (lane >> 4) * 8;
  for (int t = 0; t < NT; ++t) {
    int buf = t & 1;
    if (t + 1 < NT) stage(buf ^ 1, (t + 1) * 32);
    us8 a[4], b[4];
#pragma unroll
    for (int i = 0; i < 4; ++i) {
      a[i] = *(const us8*)&As[buf][(wr * 64 + i * 16 + lrow) * 32 + lk];
      b[i] = *(const us8*)&Bs[buf][(wc * 64 + i * 16 + lrow) * 32 + lk];
    }
#pragma unroll
    for (int i = 0; i < 4; ++i)
#pragma unroll
      for (int j = 0; j < 4; ++j)
        acc[i][j] = mfma16(a[i], b[j], acc[i][j]);
    __syncthreads();
  }

  int lg = lane >> 4;
#pragma unroll
  for (int i = 0; i < 4; ++i) {
#pragma unroll
    for (int j = 0; j < 4; ++j) {
      int col = n0 + wc * 64 + j * 16 + lrow;
#pragma unroll
      for (int r = 0; r < 4; ++r) {
        int row = m0 + wr * 64 + i * 16 + lg * 4 + r;
        float v = acc[i][j][r];
        if (MODE == 0) {
          int c = col & 1023;
          float bb; u16* dst;
          if (col < 1024)      { bb = bias0[c]; dst = out_q; }
          else if (col < 2048) { bb = bias1[c]; dst = out_k; }
          else                 { bb = bias2[c]; dst = out_v; }
          dst[(size_t)row * 1024 + c] = f2bf(v + bb);
        } else {
          out_f[(size_t)row * 1024 + col] = v + bias0[col];
        }
      }
    }
  }
}

// ---------------- varlen flash attention ------------------------------------
// grid (T/64, H); block 256 = 4 waves, wave handles 16 q-rows
__global__ __launch_bounds__(256, 2) void attn_varlen(
    const u16* __restrict__ Qb, const u16* __restrict__ Kb,
    const u16* __restrict__ Vb, const int* __restrict__ cu,
    u16* __restrict__ Ctx) {
  __shared__ u16 Ks[64 * 64];       // [key][d], swizzled
  __shared__ u16 Vts[64 * 64];      // [d][key], swizzled
  __shared__ u16 Ps[4][16 * 64];    // per-wave [q][key], swizzled

  int qt = blockIdx.x, h = blockIdx.y;
  int q0 = qt * 64;
  int tid = threadIdx.x, lane = tid & 63, wave = tid >> 6;
  int lrow = lane & 15, lg = lane >> 4;

  int cuv[NSEG + 1];
#pragma unroll
  for (int i = 0; i <= NSEG; ++i) cuv[i] = cu[i];

  int kbeg[4], kendr[4];
#pragma unroll
  for (int r = 0; r < 4; ++r) {
    int q = q0 + wave * 16 + lg * 4 + r;
    int s = 0;
#pragma unroll
    for (int i = 1; i < NSEG; ++i) if (q >= cuv[i]) s = i;
    kbeg[r] = cuv[s]; kendr[r] = cuv[s + 1];
  }
  int seg_lo = 0, seg_hi = 0;
#pragma unroll
  for (int i = 1; i < NSEG; ++i) {
    if (q0 >= cuv[i]) seg_lo = i;
    if (q0 + 63 >= cuv[i]) seg_hi = i;
  }
  int kstart = cuv[seg_lo], kend = cuv[seg_hi + 1];

  us8 qf[2];
  {
    const u16* qp = Qb + (size_t)(q0 + wave * 16 + lrow) * E_DIM + h * D_HD;
    qf[0] = *(const us8*)(qp + lg * 8);
    qf[1] = *(const us8*)(qp + 32 + lg * 8);
  }

  f32x4 accO[4] = {};
  float mrun[4], lrun[4];
#pragma unroll
  for (int r = 0; r < 4; ++r) { mrun[r] = -1e30f; lrun[r] = 0.f; }
  const float scale = 0.125f;

  for (int kt = kstart; kt < kend; kt += 64) {
    __syncthreads();
    // stage K tile and transposed V tile
    for (int c = tid; c < 512; c += 256) {
      int key = c >> 3, d0 = (c & 7) * 8;
      int kg = kt + key; if (kg > T_TOK - 1) kg = T_TOK - 1;
      us8 kv = *(const us8*)(Kb + (size_t)kg * E_DIM + h * D_HD + d0);
      us8 vv = *(const us8*)(Vb + (size_t)kg * E_DIM + h * D_HD + d0);
      int kb = key * 128 + d0 * 2;
      *(us8*)((char*)Ks + (kb ^ ((key & 7) << 4))) = kv;
#pragma unroll
      for (int j = 0; j < 8; ++j) {
        int d = d0 + j;
        int vb_ = d * 128 + key * 2;
        *(u16*)((char*)Vts + (vb_ ^ ((d & 7) << 4))) = vv[j];
      }
    }
    __syncthreads();

    // S = Q K^T  (rows: q=lg*4+r, cols: key=f*16+lrow)
    f32x4 s_[4] = {};
#pragma unroll
    for (int f = 0; f < 4; ++f) {
#pragma unroll
      for (int ks = 0; ks < 2; ++ks) {
        int row = f * 16 + lrow;
        int byte_ = row * 128 + (ks * 32 + lg * 8) * 2;
        us8 kf = *(const us8*)((char*)Ks + (byte_ ^ ((row & 7) << 4)));
        s_[f] = mfma16(qf[ks], kf, s_[f]);
      }
    }

    float scf[4];
#pragma unroll
    for (int r = 0; r < 4; ++r) {
#pragma unroll
      for (int f = 0; f < 4; ++f) {
        int key = kt + f * 16 + lrow;
        float sv = s_[f][r] * scale;
        s_[f][r] = (key >= kbeg[r] && key < kendr[r]) ? sv : -1e30f;
      }
      float tm = fmaxf(fmaxf(s_[0][r], s_[1][r]), fmaxf(s_[2][r], s_[3][r]));
      tm = fmaxf(tm, __shfl_xor(tm, 1));
      tm = fmaxf(tm, __shfl_xor(tm, 2));
      tm = fmaxf(tm, __shfl_xor(tm, 4));
      tm = fmaxf(tm, __shfl_xor(tm, 8));
      float mn = fmaxf(mrun[r], tm);
      scf[r] = __expf(mrun[r] - mn);
      mrun[r] = mn;
      float ts = 0.f;
#pragma unroll
      for (int f = 0; f < 4; ++f) {
        float p = __expf(s_[f][r] - mn);
        s_[f][r] = p;
        ts += p;
      }
      ts += __shfl_xor(ts, 1); ts += __shfl_xor(ts, 2);
      ts += __shfl_xor(ts, 4); ts += __shfl_xor(ts, 8);
      lrun[r] = lrun[r] * scf[r] + ts;
    }

#pragma unroll
    for (int nf = 0; nf < 4; ++nf)
#pragma unroll
      for (int r = 0; r < 4; ++r) accO[nf][r] *= scf[r];

    // P -> per-wave LDS (bf16, swizzled rows)
#pragma unroll
    for (int f = 0; f < 4; ++f) {
#pragma unroll
      for (int r = 0; r < 4; ++r) {
        int qv = lg * 4 + r;
        int key = f * 16 + lrow;
        int byte_ = qv * 128 + key * 2;
        *(u16*)((char*)Ps[wave] + (byte_ ^ ((qv & 7) << 4))) = f2bf(s_[f][r]);
      }
    }

    // O += P V
#pragma unroll
    for (int ks = 0; ks < 2; ++ks) {
      int byte_p = lrow * 128 + (ks * 32 + lg * 8) * 2;
      us8 pf = *(const us8*)((char*)Ps[wave] + (byte_p ^ ((lrow & 7) << 4)));
#pragma unroll
      for (int nf = 0; nf < 4; ++nf) {
        int vrow = nf * 16 + lrow;
        int byte_v = vrow * 128 + (ks * 32 + lg * 8) * 2;
        us8 vf = *(const us8*)((char*)Vts + (byte_v ^ ((vrow & 7) << 4)));
        accO[nf] = mfma16(pf, vf, accO[nf]);
      }
    }
  }

#pragma unroll
  for (int r = 0; r < 4; ++r) {
    float inv = 1.f / lrun[r];
    int q = q0 + wave * 16 + lg * 4 + r;
#pragma unroll
    for (int nf = 0; nf < 4; ++nf) {
      Ctx[(size_t)q * E_DIM + h * D_HD + nf * 16 + lrow] = f2bf(accO[nf][r] * inv);
    }
  }
}

// ---------------------------------------------------------------------------
extern "C" void kernel_launch(void* const* d_in, const int* in_sizes, int n_in,
                              void* d_out, int out_size, void* d_ws, size_t ws_size,
                              hipStream_t stream) {
  const float* hs = (const float*)d_in[0];
  const int*   cu = (const int*)d_in[1];
  const float* Wq = (const float*)d_in[2];
  const float* bq = (const float*)d_in[3];
  const float* Wk = (const float*)d_in[4];
  const float* bk = (const float*)d_in[5];
  const float* Wv = (const float*)d_in[6];
  const float* bv = (const float*)d_in[7];
  const float* Wo = (const float*)d_in[8];
  const float* bo = (const float*)d_in[9];
  float* out = (float*)d_out;

  char* ws = (char*)d_ws;
  u16* Xb   = (u16*)(ws);
  u16* Wqkv = (u16*)(ws + 8ll * 1024 * 1024);
  u16* Wob  = (u16*)(ws + 14ll * 1024 * 1024);
  u16* Qb   = (u16*)(ws + 16ll * 1024 * 1024);
  u16* Kb   = (u16*)(ws + 24ll * 1024 * 1024);
  u16* Vb   = (u16*)(ws + 32ll * 1024 * 1024);
  u16* Ctx  = (u16*)(ws + 40ll * 1024 * 1024);

  cvt_all<<<8192, 256, 0, stream>>>(hs, Wq, Wk, Wv, Wo, Xb, Wqkv, Wob);
  gemm_bt<0><<<dim3(32 * 24), 256, 0, stream>>>(Xb, Wqkv, T_TOK, 3 * E_DIM, E_DIM,
                                                bq, bk, bv, Qb, Kb, Vb, nullptr);
  attn_varlen<<<dim3(T_TOK / 64, H_N), 256, 0, stream>>>(Qb, Kb, Vb, cu, Ctx);
  gemm_bt<1><<<dim3(32 * 8), 256, 0, stream>>>(Ctx, Wob, T_TOK, E_DIM, E_DIM,
                                               bo, nullptr, nullptr,
                                               nullptr, nullptr, nullptr, out);
}